// Round 6
// baseline (2037.901 us; speedup 1.0000x reference)
//
#include <hip/hip_runtime.h>
#include <hip/hip_fp16.h>
#include <math.h>

#define BIGF   57344.0f          // == half 0x7B00, exactly representable
#define BIG2   0x7B007B00u
#define MAXSETS 8                // concurrent 4-quadrant sweep sets (early exit ~4)

// ws layout: [0,256K) u_out fp32[256][256]   (same region R1-R4 used safely)

__device__ __forceinline__ float relax1(float u0, float a, float b, float fh) {
    float one  = fminf(a, b) + fh;
    float diff = a - b;
    float disc = fmaxf(2.0f * fh * fh - diff * diff, 0.0f);
    float two  = 0.5f * (a + b + sqrtf(disc));
    float cand = (fabsf(diff) >= fh) ? one : two;
    return fminf(u0, cand);
}

__device__ __forceinline__ unsigned short f2h_up(float x) {
    __half h = __float2half(x);                      // RNE
    if (__half2float(h) < x)                         // round UP -> table stays >= u*
        h = __ushort_as_half((unsigned short)(__half_as_ushort(h) + 1));
    return __half_as_ushort(h);
}

// ---------------- full-grid concurrent-quadrant wavefront solver ----------------
// 1 block x 256 threads. Wave w sweeps quadrant w over the whole 256x256 grid:
// lane l owns logical columns C=4l..4l+3 (physical x = C or 255-C per xflip); at
// step s it relaxes the cells on logical anti-diagonal s. Fresh upwind values flow
// through fp32 registers: own-column y-upwind = own register from step s-1;
// x-upwind for K=1..3 = register of K-1 (prev step); for K=0 = neighbor lane's K=3
// register via one shfl. u lives in LDS as round-up fp16 [256][256] (upper bound of
// u* always). All 4 quadrant waves run concurrently; min-writes race benignly
// (monotone, >= u*). A set in which NO thread improves any cell certifies
// u <= relax(a_w,b_w) for all 4 {left,right}x{down,up} combos; since the combo set
// is the full product, min over combos = Godunov candidate => Godunov fixed point.
__global__ __launch_bounds__(256) void eik_solve(const float* __restrict__ f,
                                                 const float* __restrict__ src,
                                                 float* __restrict__ u_out) {
    __shared__ unsigned short uW[65536];             // fp16 u, flat [x][y], 128 KB
    const int t = threadIdx.x, l = t & 63, w = t >> 6;

    // init u = BIG
    {
        unsigned int* p = (unsigned int*)uW;
        for (int i = t; i < 32768; i += 256) p[i] = BIG2;
    }
    __syncthreads();
    // seed the 4 cells around the source (fp32 exact, round-up stored)
    if (t < 4) {
        float sx = src[0], sy = src[1];
        int ix0 = (int)fminf(fmaxf(floorf(sx), 0.f), 254.f);
        int iy0 = (int)fminf(fmaxf(floorf(sy), 0.f), 254.f);
        int gx = ix0 + (t >> 1), gy = iy0 + (t & 1);
        float dx = (float)gx - sx, dy = (float)gy - sy;
        float v = sqrtf(dx * dx + dy * dy) * f[(gx << 8) + gy];
        uW[(gx << 8) + gy] = f2h_up(v);
    }
    __syncthreads();

    // wave-uniform quadrant parameters
    const int xflip = w & 1, yflip = (w >> 1) & 1;
    const int C0 = l << 2;
    const int xk0 = xflip ? 255 - C0 : C0;
    const int dxk = xflip ? -1 : 1;                  // physical x step per K
    // per-K physical row bases (x fixed for the whole sweep)
    const int ub0 = (xk0) << 8,            ub1 = (xk0 + dxk) << 8;
    const int ub2 = (xk0 + 2 * dxk) << 8,  ub3 = (xk0 + 3 * dxk) << 8;
    const float* fB0 = f + ub0; const float* fB1 = f + ub1;
    const float* fB2 = f + ub2; const float* fB3 = f + ub3;

    // physical y from logical step position (clamped; inactive steps harmless)
#define YPHYS(S, K) ({ int yl_ = (S) - C0 - (K);                                \
                       int yc_ = min(max(yl_, 0), 255);                         \
                       yflip ? 255 - yc_ : yc_; })

#define KSTEP(K, XM, YM, UN) {                                                  \
        const int Y  = Yb - (K);                                                \
        const int ycp = yflip ? 255 - min(max(Y, 0), 255)                       \
                              : min(max(Y, 0), 255);                            \
        const int off = ub##K + ycp;                                            \
        unsigned short ob = uW[off];                                            \
        float u0 = __half2float(__ushort_as_half(ob));                          \
        float nu = relax1(u0, (XM), (YM), fr##K[i]);                            \
        if (Y >= 0 && Y <= 255) {                                               \
            unsigned short nb = f2h_up(nu);                                     \
            if (nb < ob) { uW[off] = nb; changed = 1; }                         \
            UN = nu;                                                            \
        }                                                                       \
    }

    for (int set = 0; set < MAXSETS; ++set) {
        int changed = 0;
        float un0 = BIGF, un1 = BIGF, un2 = BIGF, un3 = BIGF;
        float fr0[8], fr1[8], fr2[8], fr3[8];
#pragma unroll
        for (int i = 0; i < 8; ++i) {                // prefetch ring prologue s=0..7
            fr0[i] = fB0[YPHYS(i, 0)];
            fr1[i] = fB1[YPHYS(i, 1)];
            fr2[i] = fB2[YPHYS(i, 2)];
            fr3[i] = fB3[YPHYS(i, 3)];
        }
        for (int sb = 0; sb < 512; sb += 8) {
#pragma unroll
            for (int i = 0; i < 8; ++i) {
                const int s_ = sb + i;
                const int Yb = s_ - C0;
                float o0 = un0, o1 = un1, o2 = un2, o3 = un3;
                float sh = __shfl_up(un3, 1, 64);    // lane l-1's col C0-1, step s-1
                if (l == 0) sh = BIGF;               // logical x = -1 boundary
                KSTEP(0, sh, o0, un0)
                KSTEP(1, o0, o1, un1)
                KSTEP(2, o1, o2, un2)
                KSTEP(3, o2, o3, un3)
                fr0[i] = fB0[YPHYS(s_ + 8, 0)];      // refill ring for step s_+8
                fr1[i] = fB1[YPHYS(s_ + 8, 1)];
                fr2[i] = fB2[YPHYS(s_ + 8, 2)];
                fr3[i] = fB3[YPHYS(s_ + 8, 3)];
            }
        }
        if (__syncthreads_count(changed) == 0) break;   // clean set => fixed point
    }
    __syncthreads();

    // writeback fp16 -> fp32 table for interp
    for (int idx = t; idx < 65536; idx += 256)
        u_out[idx] = __half2float(__ushort_as_half(uW[idx]));
#undef KSTEP
#undef YPHYS
}

// ---------------- bilinear interp at picks + add origin time ----------------
__global__ void eik_interp(const float* __restrict__ u,
                           const float* __restrict__ ex,
                           const float* __restrict__ ey,
                           const float* __restrict__ et,
                           float* __restrict__ out, int n) {
    int i = blockIdx.x * blockDim.x + threadIdx.x;
    int stride = gridDim.x * blockDim.x;
    for (; i < n; i += stride) {
        float x = ex[i], y = ey[i];
        int ix0 = (int)fminf(fmaxf(floorf(x), 0.f), 254.f);
        int iy0 = (int)fminf(fmaxf(floorf(y), 0.f), 254.f);
        float xc = fminf(fmaxf(x, 0.f), 255.f);
        float yc = fminf(fmaxf(y, 0.f), 255.f);
        float fx0 = (float)ix0, fy0 = (float)iy0;
        float wx0 = xc - fx0, wx1 = (fx0 + 1.f) - xc;
        float wy0 = yc - fy0, wy1 = (fy0 + 1.f) - yc;
        int base = (ix0 << 8) + iy0;
        float Q00 = u[base],       Q01 = u[base + 1];
        float Q10 = u[base + 256], Q11 = u[base + 257];
        float tt = Q00 * wx1 * wy1 + Q10 * wx0 * wy1
                 + Q01 * wx1 * wy0 + Q11 * wx0 * wy0;
        out[i] = et[i] + tt;
    }
}

extern "C" void kernel_launch(void* const* d_in, const int* in_sizes, int n_in,
                              void* d_out, int out_size, void* d_ws, size_t ws_size,
                              hipStream_t stream) {
    const float* f   = (const float*)d_in[0];
    const float* src = (const float*)d_in[1];
    const float* ex  = (const float*)d_in[2];
    const float* ey  = (const float*)d_in[3];
    const float* et  = (const float*)d_in[4];
    float* out   = (float*)d_out;
    float* u_out = (float*)d_ws;             // 256 KB, proven-safe ws region
    int n = in_sizes[2];

    eik_solve<<<1, 256, 0, stream>>>(f, src, u_out);
    eik_interp<<<2048, 256, 0, stream>>>(u_out, ex, ey, et, out, n);
}

// Round 7
// 2029.891 us; speedup vs baseline: 1.0039x; 1.0039x over previous
//
#include <hip/hip_runtime.h>
#include <hip/hip_fp16.h>
#include <math.h>

#define BIGF 57344.0f             // == half 0x7B00, exactly representable
#define BIG2 0x7B007B00u
#define MAXSETS 8                 // concurrent 4-quadrant sweep sets (early exit expected)
#define FPAD 272                  // front guard halfs (covers off >= -264)
#define LTOT (FPAD + 65536 + 512) // 66320 halfs = 132640 B static LDS
#define DUMMY 65900               // rel-uW store sink in tail guard (never read)

__device__ __forceinline__ float wshr1(float x, float oldv) {
    // v_mov_b32_dpp wave_shr:1 — lane i gets lane i-1's x; lane 0 gets oldv
    int r = __builtin_amdgcn_update_dpp(__float_as_int(oldv), __float_as_int(x),
                                        0x138, 0xf, 0xf, false);
    return __int_as_float(r);
}

// ---------------- full-grid concurrent-quadrant wavefront solver ----------------
// 1 block x 256 threads; u fp16 in LDS, TRANSPOSED [y<<8|x] (bank stride 2/lane).
// Wave w sweeps quadrant (w+set)&3; lane l owns logical cols C=4l..4l+3; step s
// relaxes logical anti-diagonal s. Fresh upwind flows in fp32 registers (own K-1 /
// own prev step; lane boundary via DPP wave_shr1). u0/f/offsets come from 8-deep
// prefetch rings (off the critical chain; staleness is monotone-benign). Store is
// branch-free min(nb, cur) with cur read early in the step; inactive K redirect to
// DUMMY. A set with zero lowering stores certifies the Godunov fixed point.
__global__ __launch_bounds__(256) void eik_solve(const float* __restrict__ f,
                                                 const float* __restrict__ src,
                                                 float* __restrict__ u_out) {
    __shared__ unsigned short uWs[LTOT];
    unsigned short* uW = uWs + FPAD;
    const int t = threadIdx.x, l = t & 63, wv = t >> 6;

    {   // init whole array (incl. guards) to BIG
        unsigned int* p = (unsigned int*)uWs;
        for (int i = t; i < LTOT / 2; i += 256) p[i] = BIG2;
    }
    __syncthreads();
    if (t < 4) {   // seed 4 cells around the source
        float sx = src[0], sy = src[1];
        int ix0 = (int)fminf(fmaxf(floorf(sx), 0.f), 254.f);
        int iy0 = (int)fminf(fmaxf(floorf(sy), 0.f), 254.f);
        int gx = ix0 + (t >> 1), gy = iy0 + (t & 1);
        float dx = (float)gx - sx, dy = (float)gy - sy;
        float v = sqrtf(dx * dx + dy * dy) * f[(gx << 8) + gy];
        uW[(gy << 8) + gx] = __half_as_ushort(__float2half(v));
    }
    __syncthreads();

    const int C0 = l << 2;

    for (int set = 0; set < MAXSETS; ++set) {
        const int w    = (wv + set) & 3;          // rotate quadrant per set
        const int ysgn = (w & 2) ? -1 : 1;
        const int yoff = (w & 2) ? 255 : 0;
        const int dxk  = (w & 1) ? -1 : 1;
        const int xk0  = (w & 1) ? 255 - C0 : C0;
        const int xk1 = xk0 + dxk, xk2 = xk0 + 2 * dxk, xk3 = xk0 + 3 * dxk;
        const int fxb0 = xk0 << 8, fxb1 = xk1 << 8, fxb2 = xk2 << 8, fxb3 = xk3 << 8;
        const int yo0 = yoff, yo1 = yoff - ysgn, yo2 = yoff - 2 * ysgn, yo3 = yoff - 3 * ysgn;

        unsigned uq0[8], uq1[8], uq2[8], uq3[8];  // stale u16 ring (chain injection)
        float    fq0[8], fq1[8], fq2[8], fq3[8];  // slowness ring
        int      or0[8], or1[8], or2[8], or3[8];  // LDS offset ring

#define PREF(K, XKC, SL, YBF) {                                                \
        int yp  = yo##K + ysgn * (YBF);                                        \
        int ypc = min(max(yp, -1), 256);                                       \
        int o8  = (XKC) + (ypc << 8);                                          \
        or##K[SL] = o8;                                                        \
        uq##K[SL] = (unsigned)uW[o8];                                          \
        int fyc = min(max(yp, 0), 255);                                        \
        fq##K[SL] = f[fxb##K + fyc];                                           \
    }

        #pragma unroll
        for (int i = 0; i < 8; ++i) {             // ring prologue: steps 0..7
            PREF(0, xk0, i, i - C0)
            PREF(1, xk1, i, i - C0)
            PREF(2, xk2, i, i - C0)
            PREF(3, xk3, i, i - C0)
        }

        int chg = 0;
        float un0 = BIGF, un1 = BIGF, un2 = BIGF, un3 = BIGF;

        for (int sb = 0; sb < 512; sb += 8) {
            #pragma unroll
            for (int i = 0; i < 8; ++i) {
                const int s_ = sb + i;
                const int Yb = s_ - C0;
                const int off0 = or0[i], off1 = or1[i], off2 = or2[i], off3 = or3[i];
                // early fresh reads (used ~140cy later at the stores: no stall)
                const unsigned cu0 = (unsigned)uW[off0];
                const unsigned cu1 = (unsigned)uW[off1];
                const unsigned cu2 = (unsigned)uW[off2];
                const unsigned cu3 = (unsigned)uW[off3];
                const float o0 = un0, o1 = un1, o2 = un2, o3 = un3;
                const float sh = wshr1(o3, BIGF);  // lane l-1's col C0-1, step s-1

#define RELAX(K, XM) \
                const int Y##K = Yb - K; \
                const bool act##K = ((unsigned)Y##K <= 255u); \
                float u0##K = __half2float(__ushort_as_half((unsigned short)uq##K[i])); \
                float fh##K = fq##K[i]; \
                float a##K = (XM), b##K = o##K; \
                float one##K = fminf(a##K, b##K) + fh##K; \
                float dd##K = a##K - b##K; \
                float ds##K = fmaxf(2.0f * fh##K * fh##K - dd##K * dd##K, 0.0f); \
                float tw##K = 0.5f * (a##K + b##K + sqrtf(ds##K)); \
                float cd##K = (fabsf(dd##K) >= fh##K) ? one##K : tw##K; \
                float nu##K = fminf(u0##K, cd##K); \
                unsigned nb##K = (unsigned)__half_as_ushort(__float2half(nu##K));

                RELAX(0, sh)
                RELAX(1, o0)
                RELAX(2, o1)
                RELAX(3, o2)

                // branch-free min-stores (positive halfs compare as u16)
                uW[act0 ? off0 : DUMMY] = (unsigned short)(nb0 < cu0 ? nb0 : cu0);
                uW[act1 ? off1 : DUMMY] = (unsigned short)(nb1 < cu1 ? nb1 : cu1);
                uW[act2 ? off2 : DUMMY] = (unsigned short)(nb2 < cu2 ? nb2 : cu2);
                uW[act3 ? off3 : DUMMY] = (unsigned short)(nb3 < cu3 ? nb3 : cu3);
                chg |= (act0 && nb0 < cu0) | (act1 && nb1 < cu1)
                     | (act2 && nb2 < cu2) | (act3 && nb3 < cu3);
                un0 = act0 ? nu0 : un0;
                un1 = act1 ? nu1 : un1;
                un2 = act2 ? nu2 : un2;
                un3 = act3 ? nu3 : un3;

                PREF(0, xk0, i, Yb + 8)            // refill rings for step s+8
                PREF(1, xk1, i, Yb + 8)
                PREF(2, xk2, i, Yb + 8)
                PREF(3, xk3, i, Yb + 8)
#undef RELAX
            }
        }
#undef PREF
        if (__syncthreads_count(chg) == 0) break;  // clean set => Godunov fixed point
    }
    __syncthreads();

    // writeback fp16 -> fp32 table for interp (un-transpose)
    for (int idx = t; idx < 65536; idx += 256) {
        int x = idx >> 8, y = idx & 255;
        u_out[idx] = __half2float(__ushort_as_half(uW[(y << 8) + x]));
    }
}

// ---------------- bilinear interp at picks + add origin time ----------------
__global__ void eik_interp(const float* __restrict__ u,
                           const float* __restrict__ ex,
                           const float* __restrict__ ey,
                           const float* __restrict__ et,
                           float* __restrict__ out, int n) {
    int i = blockIdx.x * blockDim.x + threadIdx.x;
    int stride = gridDim.x * blockDim.x;
    for (; i < n; i += stride) {
        float x = ex[i], y = ey[i];
        int ix0 = (int)fminf(fmaxf(floorf(x), 0.f), 254.f);
        int iy0 = (int)fminf(fmaxf(floorf(y), 0.f), 254.f);
        float xc = fminf(fmaxf(x, 0.f), 255.f);
        float yc = fminf(fmaxf(y, 0.f), 255.f);
        float fx0 = (float)ix0, fy0 = (float)iy0;
        float wx0 = xc - fx0, wx1 = (fx0 + 1.f) - xc;
        float wy0 = yc - fy0, wy1 = (fy0 + 1.f) - yc;
        int base = (ix0 << 8) + iy0;
        float Q00 = u[base],       Q01 = u[base + 1];
        float Q10 = u[base + 256], Q11 = u[base + 257];
        float tt = Q00 * wx1 * wy1 + Q10 * wx0 * wy1
                 + Q01 * wx1 * wy0 + Q11 * wx0 * wy0;
        out[i] = et[i] + tt;
    }
}

extern "C" void kernel_launch(void* const* d_in, const int* in_sizes, int n_in,
                              void* d_out, int out_size, void* d_ws, size_t ws_size,
                              hipStream_t stream) {
    const float* f   = (const float*)d_in[0];
    const float* src = (const float*)d_in[1];
    const float* ex  = (const float*)d_in[2];
    const float* ey  = (const float*)d_in[3];
    const float* et  = (const float*)d_in[4];
    float* out   = (float*)d_out;
    float* u_out = (float*)d_ws;             // 256 KB, proven-safe ws region
    int n = in_sizes[2];

    eik_solve<<<1, 256, 0, stream>>>(f, src, u_out);
    eik_interp<<<2048, 256, 0, stream>>>(u_out, ex, ey, et, out, n);
}